// Round 13
// baseline (175.027 us; speedup 1.0000x reference)
//
#include <hip/hip_runtime.h>

typedef unsigned short u16;
typedef __attribute__((ext_vector_type(8))) __bf16 bf16x8;
typedef __attribute__((ext_vector_type(4))) float f32x4;
typedef __attribute__((ext_vector_type(16))) float f32x16;
typedef __attribute__((ext_vector_type(4))) unsigned short ushort4v;
typedef __attribute__((ext_vector_type(2))) unsigned uint2v;

__device__ __forceinline__ u16 f2bf(float f) {
  unsigned u = __builtin_bit_cast(unsigned, f);
  u += 0x7fffu + ((u >> 16) & 1u);
  return (u16)(u >> 16);
}

__device__ __forceinline__ float exp2_hw(float x) {
  float r; asm("v_exp_f32 %0, %1" : "=v"(r) : "v"(x)); return r;
}
__device__ __forceinline__ unsigned cvt_pk_bf16(float a, float b) {
  unsigned r; asm("v_cvt_pk_bf16_f32 %0, %1, %2" : "=v"(r) : "v"(a), "v"(b)); return r;
}

__device__ __forceinline__ void gload_lds16(const void* g, void* l) {
  __builtin_amdgcn_global_load_lds(
      (__attribute__((address_space(1))) void*)g,
      (__attribute__((address_space(3))) void*)l, 16, 0, 0);
}

__device__ __forceinline__ void BAR() {
  asm volatile("" ::: "memory");
  __builtin_amdgcn_s_barrier();
  asm volatile("" ::: "memory");
}

#define MFMA16(a, b, c) __builtin_amdgcn_mfma_f32_16x16x32_bf16(a, b, c, 0, 0, 0)
#define MFMA32(a, b, c) __builtin_amdgcn_mfma_f32_32x32x16_bf16(a, b, c, 0, 0, 0)

// scale folded into Q at GEMM1 epilogue: 1/sqrt(64) * log2(e)
#define QSCALE 0.1803368801111204f

// ---------------- merged prep kernel ----------------

__global__ __launch_bounds__(256)
void prep_kernel(const float* __restrict__ x, const float* __restrict__ Wq,
                 const float* __restrict__ Wk, const float* __restrict__ Wv,
                 const float* __restrict__ pw, u16* __restrict__ Xb,
                 u16* __restrict__ Wcat, u16* __restrict__ PWt) {
  const int b = blockIdx.x, tid = threadIdx.x;
  if (b < 8192) {
    int i = b * 256 + tid;
    float4 v = ((const float4*)x)[i];
    union { u16 u[4]; uint2 v2; } r;
    r.u[0] = f2bf(v.x); r.u[1] = f2bf(v.y); r.u[2] = f2bf(v.z); r.u[3] = f2bf(v.w);
    ((uint2*)Xb)[i] = r.v2;
  } else if (b < 8960) {
    __shared__ u16 lds[64 * 68];
    int bb = b - 8192;
    int sel = bb >> 8, rem = bb & 255;
    int h = rem >> 4, e0 = (rem & 15) * 64;
    const float* W = (sel == 0) ? Wq : (sel == 1) ? Wk : Wv;
    const float* src = W + ((size_t)h * 1024 + e0) * 64;
#pragma unroll
    for (int i = 0; i < 4; i++) {
      int idx = i * 1024 + tid * 4;
      int e = idx >> 6, hs = idx & 63;
      float4 v = *(const float4*)&src[idx];
      u16* d = &lds[e * 68 + hs];
      d[0] = f2bf(v.x); d[1] = f2bf(v.y); d[2] = f2bf(v.z); d[3] = f2bf(v.w);
    }
    __syncthreads();
#pragma unroll
    for (int i = 0; i < 2; i++) {
      int u = i * 256 + tid;
      int hs = u >> 3, ec = u & 7;
      union { u16 q[8]; uint4 v; } ou;
#pragma unroll
      for (int e = 0; e < 8; e++) ou.q[e] = lds[(ec * 8 + e) * 68 + hs];
      size_t n = (size_t)sel * 1024 + h * 64 + hs;
      *(uint4*)&Wcat[n * 1024 + e0 + ec * 8] = ou.v;
    }
  } else {
    int i = (b - 8960) * 256 + tid;
    float4 v = ((const float4*)pw)[i];
    union { u16 u[4]; uint2 v2; } r;
    r.u[0] = f2bf(v.x); r.u[1] = f2bf(v.y); r.u[2] = f2bf(v.z); r.u[3] = f2bf(v.w);
    ((uint2*)PWt)[i] = r.v2;
  }
}

// ---------------- triple-buffered 128x256 GEMM, 2 sub-phases per K-tile ----

template<int OUT_BF16>
__global__ __launch_bounds__(512, 2)
void gemm3b(const u16* __restrict__ A, const u16* __restrict__ BT,
            void* __restrict__ Cout, const float* __restrict__ bias,
            int M, int N, int K, int qcols) {
  __shared__ u16 a_lds[3][128 * 64];
  __shared__ u16 b_lds[3][256 * 64];
  const int xcd = blockIdx.x & 7;
  const int local = blockIdx.x >> 3;
  const int by = xcd * 8 + (local & 7);   // M-chunk of 8 blocks per XCD
  const int bx = local >> 3;              // N-panel, slow
  const int tid = threadIdx.x;
  const int lane = tid & 63;
  const int w = tid >> 6;
  const int wr = w >> 2, wc = w & 3;
  const int mBase = by * 128, nBase = bx * 256;
  const int l15 = lane & 15, l4 = lane >> 4;
  const int nkt = K >> 6;

  f32x4 acc[4][4] = {};

  auto STAGE_A = [&](int s, int kt) {
#pragma unroll
    for (int j = 0; j < 2; j++) {
      int e = j * 4096 + tid * 8;
      int row = e >> 6;
      int c = ((e >> 3) & 7) ^ (row & 7);
      gload_lds16(A + (size_t)(mBase + row) * K + kt * 64 + c * 8, &a_lds[s][e]);
    }
  };
  auto STAGE_B = [&](int s, int kt) {
#pragma unroll
    for (int j = 0; j < 4; j++) {
      int e = j * 4096 + tid * 8;
      int row = e >> 6;
      int c = ((e >> 3) & 7) ^ (row & 7);
      gload_lds16(BT + (size_t)(nBase + row) * K + kt * 64 + c * 8, &b_lds[s][e]);
    }
  };

  STAGE_A(0, 0); STAGE_B(0, 0);
  STAGE_A(1, 1); STAGE_B(1, 1);
  asm volatile("s_waitcnt vmcnt(6)" ::: "memory");
  BAR();

  int s0 = 0, s1 = 1, s2 = 2;
  for (int t = 0; t < nkt; t++) {
    const int t2 = (t + 2 < nkt) ? t + 2 : t + 2 - nkt;
    bf16x8 AF[4][2], BF[2][2];

#pragma unroll
    for (int m = 0; m < 4; m++) {
      int row = wr * 64 + m * 16 + l15;
#pragma unroll
      for (int ks = 0; ks < 2; ks++) {
        int ch = (ks * 4 + l4) ^ (row & 7);
        AF[m][ks] = *(const bf16x8*)&a_lds[s0][row * 64 + ch * 8];
      }
    }
#pragma unroll
    for (int n = 0; n < 2; n++) {
      int row = wc * 64 + n * 16 + l15;
#pragma unroll
      for (int ks = 0; ks < 2; ks++) {
        int ch = (ks * 4 + l4) ^ (row & 7);
        BF[n][ks] = *(const bf16x8*)&b_lds[s0][row * 64 + ch * 8];
      }
    }
    STAGE_A(s2, t2);
    BAR();
    __builtin_amdgcn_s_setprio(1);
#pragma unroll
    for (int m = 0; m < 4; m++)
#pragma unroll
      for (int n = 0; n < 2; n++) {
        acc[m][n] = MFMA16(AF[m][0], BF[n][0], acc[m][n]);
        acc[m][n] = MFMA16(AF[m][1], BF[n][1], acc[m][n]);
      }
    __builtin_amdgcn_s_setprio(0);

#pragma unroll
    for (int n = 0; n < 2; n++) {
      int row = wc * 64 + 32 + n * 16 + l15;
#pragma unroll
      for (int ks = 0; ks < 2; ks++) {
        int ch = (ks * 4 + l4) ^ (row & 7);
        BF[n][ks] = *(const bf16x8*)&b_lds[s0][row * 64 + ch * 8];
      }
    }
    STAGE_B(s2, t2);
    BAR();
    __builtin_amdgcn_s_setprio(1);
#pragma unroll
    for (int m = 0; m < 4; m++)
#pragma unroll
      for (int n = 0; n < 2; n++) {
        acc[m][2 + n] = MFMA16(AF[m][0], BF[n][0], acc[m][2 + n]);
        acc[m][2 + n] = MFMA16(AF[m][1], BF[n][1], acc[m][2 + n]);
      }
    __builtin_amdgcn_s_setprio(0);

    asm volatile("s_waitcnt vmcnt(6)" ::: "memory");
    BAR();
    int tmp = s0; s0 = s1; s1 = s2; s2 = tmp;
  }

#pragma unroll
  for (int mi = 0; mi < 4; mi++) {
    int row = mBase + wr * 64 + mi * 16 + l4 * 4;
#pragma unroll
    for (int ni = 0; ni < 4; ni++) {
      int col = nBase + wc * 64 + ni * 16 + l15;
      float scl = (col < qcols) ? QSCALE : 1.f;
#pragma unroll
      for (int j = 0; j < 4; j++) {
        float v = acc[mi][ni][j];
        if (OUT_BF16) {
          ((u16*)Cout)[(size_t)(row + j) * N + col] = f2bf(v * scl);
        } else {
          ((float*)Cout)[(size_t)(row + j) * N + col] = v + bias[col];
        }
      }
    }
  }
}

// ---------------- V transpose: VT[hb][d][t] from QKV V-section ----------------

__global__ __launch_bounds__(256)
void vt_build(const u16* __restrict__ qkv, u16* __restrict__ vt) {
  __shared__ u16 lds[64 * 66];
  const int hb = blockIdx.x >> 5, tc = blockIdx.x & 31;
  const int t0 = tc * 64, tid = threadIdx.x;
#pragma unroll
  for (int i = 0; i < 2; i++) {
    int idx = i * 2048 + tid * 8;
    int tl = idx >> 6, d0 = idx & 63;
    int r = hb * 2048 + t0 + tl;
    const u16* src = &qkv[(size_t)(r >> 4) * 3072 + 2048 + (r & 15) * 64 + d0];
    uint4 v = *(const uint4*)src;
    u16* dst = &lds[tl * 66 + d0];
    *(unsigned*)(dst + 0) = v.x; *(unsigned*)(dst + 2) = v.y;
    *(unsigned*)(dst + 4) = v.z; *(unsigned*)(dst + 6) = v.w;
  }
  __syncthreads();
#pragma unroll
  for (int i = 0; i < 2; i++) {
    int idx = i * 2048 + tid * 8;
    int d = idx >> 6, tl0 = idx & 63;
    union { u16 u[8]; uint4 v; } ou;
#pragma unroll
    for (int e = 0; e < 8; e++) ou.u[e] = lds[(tl0 + e) * 66 + d];
    *(uint4*)&vt[(size_t)hb * 131072 + (size_t)d * 2048 + t0 + tl0] = ou.v;
  }
}

// ---------------- flash attention (causal), split-K, 32x32 MFMA ------------
// 8 waves = (qg = w&3) x (kh = w>>2). 128 q-rows/block; K-range split in two
// balanced halves of qb+1 tiles each (no-max exp2 softmax => partials add
// linearly, no rescale). Longest serial chain: 32 -> 16 tiles. In-block merge
// through LDS (aliases dead K/V buffers). LDS 64 KB -> 2 blocks/CU.

__global__ __launch_bounds__(512)
void attn_kernel(const u16* __restrict__ qkv, const u16* __restrict__ vtg,
                 u16* __restrict__ att) {
  __shared__ u16 k_lds[2][2][4096];   // [kh][buf][64*64]
  __shared__ u16 v_lds[2][2][4096];

  const int xcd = blockIdx.x & 7;
  const int c = blockIdx.x >> 3;          // 0..127 within XCD
  const int hb = xcd * 8 + (c & 7);       // hb-contiguous per XCD
  const int qb = 15 - (c >> 3);           // heavy blocks first (LPT)
  const int tid = threadIdx.x;
  const int lane = tid & 63, w = tid >> 6;
  const int qg = w & 3, kh = w >> 2;
  const int l31 = lane & 31, l5 = lane >> 5;
  const int qbase = qb * 128 + qg * 32;
  const int nh = qb + 1;                  // tiles per half (balanced)

  bf16x8 qf[4];
  {
    int t = qbase + l31;
    int r = hb * 2048 + t;
    size_t base = (size_t)(r >> 4) * 3072 + (r & 15) * 64;
#pragma unroll
    for (int d = 0; d < 4; d++)
      qf[d] = *(const bf16x8*)&qkv[base + d * 16 + l5 * 8];
  }

  f32x16 o0 = {}, o1 = {};
  float lp = 0.f;

  auto STAGE = [&](int khx, int buf, int kt) {
    int tl = tid & 255;
#pragma unroll
    for (int i = 0; i < 2; i++) {
      int U = i * 2048 + tl * 8;
      int row = U >> 6;
      int chunk = ((U >> 3) & 7) ^ (row & 7);
      int rK = hb * 2048 + kt * 64 + row;
      gload_lds16(&qkv[(size_t)(rK >> 4) * 3072 + 1024 + (rK & 15) * 64 + chunk * 8],
                  &k_lds[khx][buf][U]);
    }
#pragma unroll
    for (int i = 0; i < 2; i++) {
      int U = i * 2048 + tl * 8;
      int row = U >> 6;
      int chunk = ((U >> 3) & 7) ^ (row & 7);
      gload_lds16(&vtg[(size_t)hb * 131072 + (size_t)row * 2048 + kt * 64 + chunk * 8],
                  &v_lds[khx][buf][U]);
    }
  };

  // prologue: each thread-half stages its K-half's first tile
  if (tid < 256) STAGE(0, 0, 0); else STAGE(1, 0, nh);
  asm volatile("s_waitcnt vmcnt(0)" ::: "memory");
  BAR();

  for (int s = 0; s < nh; s++) {
    if (s + 1 < nh) {
      if (tid < 256) STAGE(0, (s + 1) & 1, s + 1);
      else           STAGE(1, (s + 1) & 1, nh + s + 1);
    }
    const int cur = s & 1;
    const int kt = kh ? nh + s : s;
    const bool active = (kt * 64 <= qbase + 31);
    if (active) {
      const bool full = (kt * 64 + 63 <= qbase);
      const int q = qbase + l31;
#pragma unroll
      for (int kb = 0; kb < 2; kb++) {
        int krow = kb * 32 + l31;
        int ksw = krow & 7;
        f32x16 st = {};
        __builtin_amdgcn_s_setprio(1);
#pragma unroll
        for (int t = 0; t < 4; t++) {
          bf16x8 kf = *(const bf16x8*)&k_lds[kh][cur][krow * 64 + ((t * 2 + l5) ^ ksw) * 8];
          st = MFMA32(kf, qf[t], st);
        }
        __builtin_amdgcn_s_setprio(0);
        float p[16];
#pragma unroll
        for (int r = 0; r < 16; r++) {
          float v = st[r];
          if (!full) {
            int k = kt * 64 + kb * 32 + (r & 3) + 8 * (r >> 2) + 4 * l5;
            v = (k > q) ? -INFINITY : v;
          }
          p[r] = exp2_hw(v);
        }
        // tree-sum (shorter dependent chain than serial adds)
        float ps = ((p[0] + p[1]) + (p[2] + p[3])) + ((p[4] + p[5]) + (p[6] + p[7]));
        ps += ((p[8] + p[9]) + (p[10] + p[11])) + ((p[12] + p[13]) + (p[14] + p[15]));
        lp += ps;
#pragma unroll
        for (int kc = 0; kc < 2; kc++) {
          unsigned w0 = cvt_pk_bf16(p[kc * 8 + 0], p[kc * 8 + 1]);
          unsigned w1 = cvt_pk_bf16(p[kc * 8 + 2], p[kc * 8 + 3]);
          unsigned w2 = cvt_pk_bf16(p[kc * 8 + 4], p[kc * 8 + 5]);
          unsigned w3 = cvt_pk_bf16(p[kc * 8 + 6], p[kc * 8 + 7]);
          uint2v sw0 = __builtin_amdgcn_permlane32_swap(w0, w2, false, false);
          uint2v sw1 = __builtin_amdgcn_permlane32_swap(w1, w3, false, false);
          union { unsigned u[4]; bf16x8 v; } pf;
          pf.u[0] = sw0.x; pf.u[1] = sw1.x; pf.u[2] = sw0.y; pf.u[3] = sw1.y;
          __builtin_amdgcn_s_setprio(1);
          {
            int row0 = l31;
            int ch0 = (kb * 4 + kc * 2 + l5) ^ (row0 & 7);
            bf16x8 vf0 = *(const bf16x8*)&v_lds[kh][cur][row0 * 64 + ch0 * 8];
            o0 = MFMA32(vf0, pf.v, o0);
            int row1 = 32 + l31;
            int ch1 = (kb * 4 + kc * 2 + l5) ^ (row1 & 7);
            bf16x8 vf1 = *(const bf16x8*)&v_lds[kh][cur][row1 * 64 + ch1 * 8];
            o1 = MFMA32(vf1, pf.v, o1);
          }
          __builtin_amdgcn_s_setprio(0);
        }
      }
    }
    asm volatile("s_waitcnt vmcnt(0)" ::: "memory");
    BAR();
  }

  // ---- split-K merge: partials add linearly (no-max softmax) ----
  float* fo = (float*)&k_lds[0][0][0];   // 8192 floats = 32 KB (aliases dead K bufs)
  float* fl = (float*)&v_lds[0][0][0];   // 256 floats  (aliases dead V bufs)
  if (kh == 1) {
    float* dst = fo + ((qg * 64 + lane) << 5);
#pragma unroll
    for (int r = 0; r < 16; r++) { dst[r] = o0[r]; dst[16 + r] = o1[r]; }
    fl[qg * 64 + lane] = lp;
  }
  __syncthreads();
  if (kh == 0) {
    const float* src = fo + ((qg * 64 + lane) << 5);
#pragma unroll
    for (int r = 0; r < 16; r++) { o0[r] += src[r]; o1[r] += src[16 + r]; }
    lp += fl[qg * 64 + lane];
    lp += __shfl_xor(lp, 32);
    float rl = 1.f / lp;
    int q = qbase + l31;
    size_t rbase = ((size_t)hb * 2048 + q) * 64;
#pragma unroll
    for (int g = 0; g < 4; g++) {
      uint2 wv;
      wv.x = cvt_pk_bf16(o0[4 * g + 0] * rl, o0[4 * g + 1] * rl);
      wv.y = cvt_pk_bf16(o0[4 * g + 2] * rl, o0[4 * g + 3] * rl);
      *(uint2*)&att[rbase + g * 8 + 4 * l5] = wv;
      uint2 wu;
      wu.x = cvt_pk_bf16(o1[4 * g + 0] * rl, o1[4 * g + 1] * rl);
      wu.y = cvt_pk_bf16(o1[4 * g + 2] * rl, o1[4 * g + 3] * rl);
      *(uint2*)&att[rbase + 32 + g * 8 + 4 * l5] = wu;
    }
  }
}

// ---------------- launch ----------------

extern "C" void kernel_launch(void* const* d_in, const int* in_sizes, int n_in,
                              void* d_out, int out_size, void* d_ws, size_t ws_size,
                              hipStream_t stream) {
  const float* x  = (const float*)d_in[0];
  const float* Wq = (const float*)d_in[1];
  const float* Wk = (const float*)d_in[2];
  const float* Wv = (const float*)d_in[3];
  const float* pw = (const float*)d_in[4];
  const float* pb = (const float*)d_in[5];
  float* out = (float*)d_out;

  char* ws = (char*)d_ws;
  u16* Xb   = (u16*)(ws);                       // 16 MB (dead after GEMM1)
  u16* VTg  = (u16*)(ws);                       // 16 MB (overlays Xb)
  u16* Wcat = (u16*)(ws + (16u << 20));         // 6 MB
  u16* PWt  = (u16*)(ws + (22u << 20));         // 2 MB
  u16* QKV  = (u16*)(ws + (24u << 20));         // 48 MB
  u16* ATT  = (u16*)(ws + (72u << 20));         // 16 MB (total 88 MB)

  prep_kernel<<<9984, 256, 0, stream>>>(x, Wq, Wk, Wv, pw, Xb, Wcat, PWt);

  gemm3b<1><<<768, 512, 0, stream>>>(Xb, Wcat, QKV, nullptr, 8192, 3072, 1024, 1024);

  vt_build<<<2048, 256, 0, stream>>>(QKV, VTg);

  attn_kernel<<<1024, 512, 0, stream>>>(QKV, VTg, ATT);

  gemm3b<0><<<256, 512, 0, stream>>>(ATT, PWt, out, pb, 8192, 1024, 1024, 0);
}

// Round 14
// 169.727 us; speedup vs baseline: 1.0312x; 1.0312x over previous
//
#include <hip/hip_runtime.h>

typedef unsigned short u16;
typedef __attribute__((ext_vector_type(8))) __bf16 bf16x8;
typedef __attribute__((ext_vector_type(4))) float f32x4;
typedef __attribute__((ext_vector_type(16))) float f32x16;
typedef __attribute__((ext_vector_type(4))) unsigned short ushort4v;
typedef __attribute__((ext_vector_type(2))) unsigned uint2v;

__device__ __forceinline__ u16 f2bf(float f) {
  unsigned u = __builtin_bit_cast(unsigned, f);
  u += 0x7fffu + ((u >> 16) & 1u);
  return (u16)(u >> 16);
}

__device__ __forceinline__ float exp2_hw(float x) {
  float r; asm("v_exp_f32 %0, %1" : "=v"(r) : "v"(x)); return r;
}
__device__ __forceinline__ unsigned cvt_pk_bf16(float a, float b) {
  unsigned r; asm("v_cvt_pk_bf16_f32 %0, %1, %2" : "=v"(r) : "v"(a), "v"(b)); return r;
}

__device__ __forceinline__ void gload_lds16(const void* g, void* l) {
  __builtin_amdgcn_global_load_lds(
      (__attribute__((address_space(1))) void*)g,
      (__attribute__((address_space(3))) void*)l, 16, 0, 0);
}

__device__ __forceinline__ void BAR() {
  asm volatile("" ::: "memory");
  __builtin_amdgcn_s_barrier();
  asm volatile("" ::: "memory");
}

#define MFMA16(a, b, c) __builtin_amdgcn_mfma_f32_16x16x32_bf16(a, b, c, 0, 0, 0)
#define MFMA32(a, b, c) __builtin_amdgcn_mfma_f32_32x32x16_bf16(a, b, c, 0, 0, 0)

// scale folded into Q at GEMM1 epilogue: 1/sqrt(64) * log2(e)
#define QSCALE 0.1803368801111204f

// ---------------- merged prep kernel ----------------

__global__ __launch_bounds__(256)
void prep_kernel(const float* __restrict__ x, const float* __restrict__ Wq,
                 const float* __restrict__ Wk, const float* __restrict__ Wv,
                 const float* __restrict__ pw, u16* __restrict__ Xb,
                 u16* __restrict__ Wcat, u16* __restrict__ PWt) {
  const int b = blockIdx.x, tid = threadIdx.x;
  if (b < 8192) {
    int i = b * 256 + tid;
    float4 v = ((const float4*)x)[i];
    union { u16 u[4]; uint2 v2; } r;
    r.u[0] = f2bf(v.x); r.u[1] = f2bf(v.y); r.u[2] = f2bf(v.z); r.u[3] = f2bf(v.w);
    ((uint2*)Xb)[i] = r.v2;
  } else if (b < 8960) {
    __shared__ u16 lds[64 * 68];
    int bb = b - 8192;
    int sel = bb >> 8, rem = bb & 255;
    int h = rem >> 4, e0 = (rem & 15) * 64;
    const float* W = (sel == 0) ? Wq : (sel == 1) ? Wk : Wv;
    const float* src = W + ((size_t)h * 1024 + e0) * 64;
#pragma unroll
    for (int i = 0; i < 4; i++) {
      int idx = i * 1024 + tid * 4;
      int e = idx >> 6, hs = idx & 63;
      float4 v = *(const float4*)&src[idx];
      u16* d = &lds[e * 68 + hs];
      d[0] = f2bf(v.x); d[1] = f2bf(v.y); d[2] = f2bf(v.z); d[3] = f2bf(v.w);
    }
    __syncthreads();
#pragma unroll
    for (int i = 0; i < 2; i++) {
      int u = i * 256 + tid;
      int hs = u >> 3, ec = u & 7;
      union { u16 q[8]; uint4 v; } ou;
#pragma unroll
      for (int e = 0; e < 8; e++) ou.q[e] = lds[(ec * 8 + e) * 68 + hs];
      size_t n = (size_t)sel * 1024 + h * 64 + hs;
      *(uint4*)&Wcat[n * 1024 + e0 + ec * 8] = ou.v;
    }
  } else {
    int i = (b - 8960) * 256 + tid;
    float4 v = ((const float4*)pw)[i];
    union { u16 u[4]; uint2 v2; } r;
    r.u[0] = f2bf(v.x); r.u[1] = f2bf(v.y); r.u[2] = f2bf(v.z); r.u[3] = f2bf(v.w);
    ((uint2*)PWt)[i] = r.v2;
  }
}

// ---------------- triple-buffered 128x256 GEMM, 2 sub-phases per K-tile ----

template<int OUT_BF16>
__global__ __launch_bounds__(512, 2)
void gemm3b(const u16* __restrict__ A, const u16* __restrict__ BT,
            void* __restrict__ Cout, const float* __restrict__ bias,
            int M, int N, int K, int qcols) {
  __shared__ u16 a_lds[3][128 * 64];
  __shared__ u16 b_lds[3][256 * 64];
  const int xcd = blockIdx.x & 7;
  const int local = blockIdx.x >> 3;
  const int by = xcd * 8 + (local & 7);   // M-chunk of 8 blocks per XCD
  const int bx = local >> 3;              // N-panel, slow
  const int tid = threadIdx.x;
  const int lane = tid & 63;
  const int w = tid >> 6;
  const int wr = w >> 2, wc = w & 3;
  const int mBase = by * 128, nBase = bx * 256;
  const int l15 = lane & 15, l4 = lane >> 4;
  const int nkt = K >> 6;

  f32x4 acc[4][4] = {};

  auto STAGE_A = [&](int s, int kt) {
#pragma unroll
    for (int j = 0; j < 2; j++) {
      int e = j * 4096 + tid * 8;
      int row = e >> 6;
      int c = ((e >> 3) & 7) ^ (row & 7);
      gload_lds16(A + (size_t)(mBase + row) * K + kt * 64 + c * 8, &a_lds[s][e]);
    }
  };
  auto STAGE_B = [&](int s, int kt) {
#pragma unroll
    for (int j = 0; j < 4; j++) {
      int e = j * 4096 + tid * 8;
      int row = e >> 6;
      int c = ((e >> 3) & 7) ^ (row & 7);
      gload_lds16(BT + (size_t)(nBase + row) * K + kt * 64 + c * 8, &b_lds[s][e]);
    }
  };

  STAGE_A(0, 0); STAGE_B(0, 0);
  STAGE_A(1, 1); STAGE_B(1, 1);
  asm volatile("s_waitcnt vmcnt(6)" ::: "memory");
  BAR();

  int s0 = 0, s1 = 1, s2 = 2;
  for (int t = 0; t < nkt; t++) {
    const int t2 = (t + 2 < nkt) ? t + 2 : t + 2 - nkt;
    bf16x8 AF[4][2], BF[2][2];

#pragma unroll
    for (int m = 0; m < 4; m++) {
      int row = wr * 64 + m * 16 + l15;
#pragma unroll
      for (int ks = 0; ks < 2; ks++) {
        int ch = (ks * 4 + l4) ^ (row & 7);
        AF[m][ks] = *(const bf16x8*)&a_lds[s0][row * 64 + ch * 8];
      }
    }
#pragma unroll
    for (int n = 0; n < 2; n++) {
      int row = wc * 64 + n * 16 + l15;
#pragma unroll
      for (int ks = 0; ks < 2; ks++) {
        int ch = (ks * 4 + l4) ^ (row & 7);
        BF[n][ks] = *(const bf16x8*)&b_lds[s0][row * 64 + ch * 8];
      }
    }
    STAGE_A(s2, t2);
    BAR();
    __builtin_amdgcn_s_setprio(1);
#pragma unroll
    for (int m = 0; m < 4; m++)
#pragma unroll
      for (int n = 0; n < 2; n++) {
        acc[m][n] = MFMA16(AF[m][0], BF[n][0], acc[m][n]);
        acc[m][n] = MFMA16(AF[m][1], BF[n][1], acc[m][n]);
      }
    __builtin_amdgcn_s_setprio(0);

#pragma unroll
    for (int n = 0; n < 2; n++) {
      int row = wc * 64 + 32 + n * 16 + l15;
#pragma unroll
      for (int ks = 0; ks < 2; ks++) {
        int ch = (ks * 4 + l4) ^ (row & 7);
        BF[n][ks] = *(const bf16x8*)&b_lds[s0][row * 64 + ch * 8];
      }
    }
    STAGE_B(s2, t2);
    BAR();
    __builtin_amdgcn_s_setprio(1);
#pragma unroll
    for (int m = 0; m < 4; m++)
#pragma unroll
      for (int n = 0; n < 2; n++) {
        acc[m][2 + n] = MFMA16(AF[m][0], BF[n][0], acc[m][2 + n]);
        acc[m][2 + n] = MFMA16(AF[m][1], BF[n][1], acc[m][2 + n]);
      }
    __builtin_amdgcn_s_setprio(0);

    asm volatile("s_waitcnt vmcnt(6)" ::: "memory");
    BAR();
    int tmp = s0; s0 = s1; s1 = s2; s2 = tmp;
  }

#pragma unroll
  for (int mi = 0; mi < 4; mi++) {
    int row = mBase + wr * 64 + mi * 16 + l4 * 4;
#pragma unroll
    for (int ni = 0; ni < 4; ni++) {
      int col = nBase + wc * 64 + ni * 16 + l15;
      float scl = (col < qcols) ? QSCALE : 1.f;
#pragma unroll
      for (int j = 0; j < 4; j++) {
        float v = acc[mi][ni][j];
        if (OUT_BF16) {
          ((u16*)Cout)[(size_t)(row + j) * N + col] = f2bf(v * scl);
        } else {
          ((float*)Cout)[(size_t)(row + j) * N + col] = v + bias[col];
        }
      }
    }
  }
}

// ---------------- V transpose: VT[hb][d][t] from QKV V-section ----------------

__global__ __launch_bounds__(256)
void vt_build(const u16* __restrict__ qkv, u16* __restrict__ vt) {
  __shared__ u16 lds[64 * 66];
  const int hb = blockIdx.x >> 5, tc = blockIdx.x & 31;
  const int t0 = tc * 64, tid = threadIdx.x;
#pragma unroll
  for (int i = 0; i < 2; i++) {
    int idx = i * 2048 + tid * 8;
    int tl = idx >> 6, d0 = idx & 63;
    int r = hb * 2048 + t0 + tl;
    const u16* src = &qkv[(size_t)(r >> 4) * 3072 + 2048 + (r & 15) * 64 + d0];
    uint4 v = *(const uint4*)src;
    u16* dst = &lds[tl * 66 + d0];
    *(unsigned*)(dst + 0) = v.x; *(unsigned*)(dst + 2) = v.y;
    *(unsigned*)(dst + 4) = v.z; *(unsigned*)(dst + 6) = v.w;
  }
  __syncthreads();
#pragma unroll
  for (int i = 0; i < 2; i++) {
    int idx = i * 2048 + tid * 8;
    int d = idx >> 6, tl0 = idx & 63;
    union { u16 u[8]; uint4 v; } ou;
#pragma unroll
    for (int e = 0; e < 8; e++) ou.u[e] = lds[(tl0 + e) * 66 + d];
    *(uint4*)&vt[(size_t)hb * 131072 + (size_t)d * 2048 + t0 + tl0] = ou.v;
  }
}

// ---------------- flash attention (causal), 32x32 MFMA, in-register P ------
// R12 structure (best known: 74us) + ones-row MFMA l-sum: l[q] = sum_k P[k][q]
// computed as o2 = MFMA32(ones, pf) accumulated across tiles — every output
// element equals the full sum, so o2[0] is l with zero VALU adds and no
// epilogue shuffle. Moves l-work from VALU pipe (57% busy) to MFMA (19%).

__global__ __launch_bounds__(256)
void attn_kernel(const u16* __restrict__ qkv, const u16* __restrict__ vtg,
                 u16* __restrict__ att) {
  __shared__ u16 k_lds[2][64 * 64];
  __shared__ u16 v_lds[2][64 * 64];

  const int xcd = blockIdx.x & 7;
  const int c = blockIdx.x >> 3;          // 0..127 within XCD
  const int hb = xcd * 8 + (c & 7);       // hb-contiguous per XCD
  const int qb = 15 - (c >> 3);           // heavy blocks first (LPT)
  const int tid = threadIdx.x;
  const int lane = tid & 63, w = tid >> 6;
  const int l31 = lane & 31, l5 = lane >> 5;
  const int qbase = qb * 128 + w * 32;
  const int nkt = 2 * qb + 2;

  bf16x8 qf[4];
  {
    int t = qbase + l31;
    int r = hb * 2048 + t;
    size_t base = (size_t)(r >> 4) * 3072 + (r & 15) * 64;
#pragma unroll
    for (int d = 0; d < 4; d++)
      qf[d] = *(const bf16x8*)&qkv[base + d * 16 + l5 * 8];
  }

  // ones A-fragment for the l-sum MFMA (bf16 1.0 = 0x3F80)
  bf16x8 ONES;
  {
    union { u16 u[8]; bf16x8 v; } o1s;
#pragma unroll
    for (int i = 0; i < 8; i++) o1s.u[i] = 0x3F80;
    ONES = o1s.v;
  }

  f32x16 o0 = {}, o1 = {}, o2 = {};

  auto STAGE = [&](int buf, int kt) {
#pragma unroll
    for (int i = 0; i < 2; i++) {
      int U = i * 2048 + tid * 8;
      int row = U >> 6;
      int chunk = ((U >> 3) & 7) ^ (row & 7);
      int rK = hb * 2048 + kt * 64 + row;
      gload_lds16(&qkv[(size_t)(rK >> 4) * 3072 + 1024 + (rK & 15) * 64 + chunk * 8],
                  &k_lds[buf][U]);
    }
#pragma unroll
    for (int i = 0; i < 2; i++) {
      int U = i * 2048 + tid * 8;
      int row = U >> 6;
      int chunk = ((U >> 3) & 7) ^ (row & 7);
      gload_lds16(&vtg[(size_t)hb * 131072 + (size_t)row * 2048 + kt * 64 + chunk * 8],
                  &v_lds[buf][U]);
    }
  };

  STAGE(0, 0);
  asm volatile("s_waitcnt vmcnt(0)" ::: "memory");
  BAR();

  for (int kt = 0; kt < nkt; kt++) {
    if (kt + 1 < nkt) STAGE((kt + 1) & 1, kt + 1);
    const int cur = kt & 1;
    const bool active = (kt * 64 <= qbase + 31);
    if (active) {
      const bool full = (kt * 64 + 63 <= qbase);
      const int q = qbase + l31;
#pragma unroll
      for (int kb = 0; kb < 2; kb++) {
        int krow = kb * 32 + l31;
        int ksw = krow & 7;
        f32x16 st = {};
        __builtin_amdgcn_s_setprio(1);
#pragma unroll
        for (int t = 0; t < 4; t++) {
          bf16x8 kf = *(const bf16x8*)&k_lds[cur][krow * 64 + ((t * 2 + l5) ^ ksw) * 8];
          st = MFMA32(kf, qf[t], st);
        }
        __builtin_amdgcn_s_setprio(0);
        float p[16];
#pragma unroll
        for (int r = 0; r < 16; r++) {
          float v = st[r];
          if (!full) {
            int k = kt * 64 + kb * 32 + (r & 3) + 8 * (r >> 2) + 4 * l5;
            v = (k > q) ? -INFINITY : v;
          }
          p[r] = exp2_hw(v);
        }
#pragma unroll
        for (int kc = 0; kc < 2; kc++) {
          unsigned w0 = cvt_pk_bf16(p[kc * 8 + 0], p[kc * 8 + 1]);
          unsigned w1 = cvt_pk_bf16(p[kc * 8 + 2], p[kc * 8 + 3]);
          unsigned w2 = cvt_pk_bf16(p[kc * 8 + 4], p[kc * 8 + 5]);
          unsigned w3 = cvt_pk_bf16(p[kc * 8 + 6], p[kc * 8 + 7]);
          uint2v sw0 = __builtin_amdgcn_permlane32_swap(w0, w2, false, false);
          uint2v sw1 = __builtin_amdgcn_permlane32_swap(w1, w3, false, false);
          union { unsigned u[4]; bf16x8 v; } pf;
          pf.u[0] = sw0.x; pf.u[1] = sw1.x; pf.u[2] = sw0.y; pf.u[3] = sw1.y;
          __builtin_amdgcn_s_setprio(1);
          {
            int row0 = l31;
            int ch0 = (kb * 4 + kc * 2 + l5) ^ (row0 & 7);
            bf16x8 vf0 = *(const bf16x8*)&v_lds[cur][row0 * 64 + ch0 * 8];
            o0 = MFMA32(vf0, pf.v, o0);
            int row1 = 32 + l31;
            int ch1 = (kb * 4 + kc * 2 + l5) ^ (row1 & 7);
            bf16x8 vf1 = *(const bf16x8*)&v_lds[cur][row1 * 64 + ch1 * 8];
            o1 = MFMA32(vf1, pf.v, o1);
            o2 = MFMA32(ONES, pf.v, o2);   // l-sum on the MFMA pipe
          }
          __builtin_amdgcn_s_setprio(0);
        }
      }
    }
    asm volatile("s_waitcnt vmcnt(0)" ::: "memory");
    BAR();
  }

  // epilogue: l = o2[0] (complete sum over all k; identical across rows)
  float rl = 1.f / o2[0];
  {
    int q = qbase + l31;
    size_t rbase = ((size_t)hb * 2048 + q) * 64;
#pragma unroll
    for (int g = 0; g < 4; g++) {
      uint2 wv;
      wv.x = cvt_pk_bf16(o0[4 * g + 0] * rl, o0[4 * g + 1] * rl);
      wv.y = cvt_pk_bf16(o0[4 * g + 2] * rl, o0[4 * g + 3] * rl);
      *(uint2*)&att[rbase + g * 8 + 4 * l5] = wv;
      uint2 wu;
      wu.x = cvt_pk_bf16(o1[4 * g + 0] * rl, o1[4 * g + 1] * rl);
      wu.y = cvt_pk_bf16(o1[4 * g + 2] * rl, o1[4 * g + 3] * rl);
      *(uint2*)&att[rbase + 32 + g * 8 + 4 * l5] = wu;
    }
  }
}

// ---------------- launch ----------------

extern "C" void kernel_launch(void* const* d_in, const int* in_sizes, int n_in,
                              void* d_out, int out_size, void* d_ws, size_t ws_size,
                              hipStream_t stream) {
  const float* x  = (const float*)d_in[0];
  const float* Wq = (const float*)d_in[1];
  const float* Wk = (const float*)d_in[2];
  const float* Wv = (const float*)d_in[3];
  const float* pw = (const float*)d_in[4];
  const float* pb = (const float*)d_in[5];
  float* out = (float*)d_out;

  char* ws = (char*)d_ws;
  u16* Xb   = (u16*)(ws);                       // 16 MB (dead after GEMM1)
  u16* VTg  = (u16*)(ws);                       // 16 MB (overlays Xb)
  u16* Wcat = (u16*)(ws + (16u << 20));         // 6 MB
  u16* PWt  = (u16*)(ws + (22u << 20));         // 2 MB
  u16* QKV  = (u16*)(ws + (24u << 20));         // 48 MB
  u16* ATT  = (u16*)(ws + (72u << 20));         // 16 MB (total 88 MB)

  prep_kernel<<<9984, 256, 0, stream>>>(x, Wq, Wk, Wv, pw, Xb, Wcat, PWt);

  gemm3b<1><<<768, 512, 0, stream>>>(Xb, Wcat, QKV, nullptr, 8192, 3072, 1024, 1024);

  vt_build<<<2048, 256, 0, stream>>>(QKV, VTg);

  attn_kernel<<<1024, 256, 0, stream>>>(QKV, VTg, ATT);

  gemm3b<0><<<256, 512, 0, stream>>>(ATT, PWt, out, pb, 8192, 1024, 1024, 0);
}

// Round 15
// 162.495 us; speedup vs baseline: 1.0771x; 1.0445x over previous
//
#include <hip/hip_runtime.h>

typedef unsigned short u16;
typedef __attribute__((ext_vector_type(8))) __bf16 bf16x8;
typedef __attribute__((ext_vector_type(4))) float f32x4;
typedef __attribute__((ext_vector_type(16))) float f32x16;
typedef __attribute__((ext_vector_type(4))) unsigned short ushort4v;
typedef __attribute__((ext_vector_type(2))) unsigned uint2v;

__device__ __forceinline__ u16 f2bf(float f) {
  unsigned u = __builtin_bit_cast(unsigned, f);
  u += 0x7fffu + ((u >> 16) & 1u);
  return (u16)(u >> 16);
}

__device__ __forceinline__ float exp2_hw(float x) {
  float r; asm("v_exp_f32 %0, %1" : "=v"(r) : "v"(x)); return r;
}
__device__ __forceinline__ unsigned cvt_pk_bf16(float a, float b) {
  unsigned r; asm("v_cvt_pk_bf16_f32 %0, %1, %2" : "=v"(r) : "v"(a), "v"(b)); return r;
}

__device__ __forceinline__ void gload_lds16(const void* g, void* l) {
  __builtin_amdgcn_global_load_lds(
      (__attribute__((address_space(1))) void*)g,
      (__attribute__((address_space(3))) void*)l, 16, 0, 0);
}

__device__ __forceinline__ void BAR() {
  asm volatile("" ::: "memory");
  __builtin_amdgcn_s_barrier();
  asm volatile("" ::: "memory");
}

#define MFMA16(a, b, c) __builtin_amdgcn_mfma_f32_16x16x32_bf16(a, b, c, 0, 0, 0)
#define MFMA32(a, b, c) __builtin_amdgcn_mfma_f32_32x32x16_bf16(a, b, c, 0, 0, 0)

// scale folded into Q at GEMM1 epilogue: 1/sqrt(64) * log2(e)
#define QSCALE 0.1803368801111204f

// ---------------- merged prep kernel ----------------

__global__ __launch_bounds__(256)
void prep_kernel(const float* __restrict__ x, const float* __restrict__ Wq,
                 const float* __restrict__ Wk, const float* __restrict__ Wv,
                 const float* __restrict__ pw, u16* __restrict__ Xb,
                 u16* __restrict__ Wcat, u16* __restrict__ PWt) {
  const int b = blockIdx.x, tid = threadIdx.x;
  if (b < 8192) {
    int i = b * 256 + tid;
    float4 v = ((const float4*)x)[i];
    union { u16 u[4]; uint2 v2; } r;
    r.u[0] = f2bf(v.x); r.u[1] = f2bf(v.y); r.u[2] = f2bf(v.z); r.u[3] = f2bf(v.w);
    ((uint2*)Xb)[i] = r.v2;
  } else if (b < 8960) {
    __shared__ u16 lds[64 * 68];
    int bb = b - 8192;
    int sel = bb >> 8, rem = bb & 255;
    int h = rem >> 4, e0 = (rem & 15) * 64;
    const float* W = (sel == 0) ? Wq : (sel == 1) ? Wk : Wv;
    const float* src = W + ((size_t)h * 1024 + e0) * 64;
#pragma unroll
    for (int i = 0; i < 4; i++) {
      int idx = i * 1024 + tid * 4;
      int e = idx >> 6, hs = idx & 63;
      float4 v = *(const float4*)&src[idx];
      u16* d = &lds[e * 68 + hs];
      d[0] = f2bf(v.x); d[1] = f2bf(v.y); d[2] = f2bf(v.z); d[3] = f2bf(v.w);
    }
    __syncthreads();
#pragma unroll
    for (int i = 0; i < 2; i++) {
      int u = i * 256 + tid;
      int hs = u >> 3, ec = u & 7;
      union { u16 q[8]; uint4 v; } ou;
#pragma unroll
      for (int e = 0; e < 8; e++) ou.q[e] = lds[(ec * 8 + e) * 68 + hs];
      size_t n = (size_t)sel * 1024 + h * 64 + hs;
      *(uint4*)&Wcat[n * 1024 + e0 + ec * 8] = ou.v;
    }
  } else {
    int i = (b - 8960) * 256 + tid;
    float4 v = ((const float4*)pw)[i];
    union { u16 u[4]; uint2 v2; } r;
    r.u[0] = f2bf(v.x); r.u[1] = f2bf(v.y); r.u[2] = f2bf(v.z); r.u[3] = f2bf(v.w);
    ((uint2*)PWt)[i] = r.v2;
  }
}

// ---------------- triple-buffered 128x256 GEMM, 2 sub-phases per K-tile ----

template<int OUT_BF16>
__global__ __launch_bounds__(512, 2)
void gemm3b(const u16* __restrict__ A, const u16* __restrict__ BT,
            void* __restrict__ Cout, const float* __restrict__ bias,
            int M, int N, int K, int qcols) {
  __shared__ u16 a_lds[3][128 * 64];
  __shared__ u16 b_lds[3][256 * 64];
  const int xcd = blockIdx.x & 7;
  const int local = blockIdx.x >> 3;
  const int by = xcd * 8 + (local & 7);   // M-chunk of 8 blocks per XCD
  const int bx = local >> 3;              // N-panel, slow
  const int tid = threadIdx.x;
  const int lane = tid & 63;
  const int w = tid >> 6;
  const int wr = w >> 2, wc = w & 3;
  const int mBase = by * 128, nBase = bx * 256;
  const int l15 = lane & 15, l4 = lane >> 4;
  const int nkt = K >> 6;

  f32x4 acc[4][4] = {};

  auto STAGE_A = [&](int s, int kt) {
#pragma unroll
    for (int j = 0; j < 2; j++) {
      int e = j * 4096 + tid * 8;
      int row = e >> 6;
      int c = ((e >> 3) & 7) ^ (row & 7);
      gload_lds16(A + (size_t)(mBase + row) * K + kt * 64 + c * 8, &a_lds[s][e]);
    }
  };
  auto STAGE_B = [&](int s, int kt) {
#pragma unroll
    for (int j = 0; j < 4; j++) {
      int e = j * 4096 + tid * 8;
      int row = e >> 6;
      int c = ((e >> 3) & 7) ^ (row & 7);
      gload_lds16(BT + (size_t)(nBase + row) * K + kt * 64 + c * 8, &b_lds[s][e]);
    }
  };

  STAGE_A(0, 0); STAGE_B(0, 0);
  STAGE_A(1, 1); STAGE_B(1, 1);
  asm volatile("s_waitcnt vmcnt(6)" ::: "memory");
  BAR();

  int s0 = 0, s1 = 1, s2 = 2;
  for (int t = 0; t < nkt; t++) {
    const int t2 = (t + 2 < nkt) ? t + 2 : t + 2 - nkt;
    bf16x8 AF[4][2], BF[2][2];

#pragma unroll
    for (int m = 0; m < 4; m++) {
      int row = wr * 64 + m * 16 + l15;
#pragma unroll
      for (int ks = 0; ks < 2; ks++) {
        int ch = (ks * 4 + l4) ^ (row & 7);
        AF[m][ks] = *(const bf16x8*)&a_lds[s0][row * 64 + ch * 8];
      }
    }
#pragma unroll
    for (int n = 0; n < 2; n++) {
      int row = wc * 64 + n * 16 + l15;
#pragma unroll
      for (int ks = 0; ks < 2; ks++) {
        int ch = (ks * 4 + l4) ^ (row & 7);
        BF[n][ks] = *(const bf16x8*)&b_lds[s0][row * 64 + ch * 8];
      }
    }
    STAGE_A(s2, t2);
    BAR();
    __builtin_amdgcn_s_setprio(1);
#pragma unroll
    for (int m = 0; m < 4; m++)
#pragma unroll
      for (int n = 0; n < 2; n++) {
        acc[m][n] = MFMA16(AF[m][0], BF[n][0], acc[m][n]);
        acc[m][n] = MFMA16(AF[m][1], BF[n][1], acc[m][n]);
      }
    __builtin_amdgcn_s_setprio(0);

#pragma unroll
    for (int n = 0; n < 2; n++) {
      int row = wc * 64 + 32 + n * 16 + l15;
#pragma unroll
      for (int ks = 0; ks < 2; ks++) {
        int ch = (ks * 4 + l4) ^ (row & 7);
        BF[n][ks] = *(const bf16x8*)&b_lds[s0][row * 64 + ch * 8];
      }
    }
    STAGE_B(s2, t2);
    BAR();
    __builtin_amdgcn_s_setprio(1);
#pragma unroll
    for (int m = 0; m < 4; m++)
#pragma unroll
      for (int n = 0; n < 2; n++) {
        acc[m][2 + n] = MFMA16(AF[m][0], BF[n][0], acc[m][2 + n]);
        acc[m][2 + n] = MFMA16(AF[m][1], BF[n][1], acc[m][2 + n]);
      }
    __builtin_amdgcn_s_setprio(0);

    asm volatile("s_waitcnt vmcnt(6)" ::: "memory");
    BAR();
    int tmp = s0; s0 = s1; s1 = s2; s2 = tmp;
  }

#pragma unroll
  for (int mi = 0; mi < 4; mi++) {
    int row = mBase + wr * 64 + mi * 16 + l4 * 4;
#pragma unroll
    for (int ni = 0; ni < 4; ni++) {
      int col = nBase + wc * 64 + ni * 16 + l15;
      float scl = (col < qcols) ? QSCALE : 1.f;
#pragma unroll
      for (int j = 0; j < 4; j++) {
        float v = acc[mi][ni][j];
        if (OUT_BF16) {
          ((u16*)Cout)[(size_t)(row + j) * N + col] = f2bf(v * scl);
        } else {
          ((float*)Cout)[(size_t)(row + j) * N + col] = v + bias[col];
        }
      }
    }
  }
}

// ---------------- V transpose: VT[hb][d][t] from QKV V-section ----------------

__global__ __launch_bounds__(256)
void vt_build(const u16* __restrict__ qkv, u16* __restrict__ vt) {
  __shared__ u16 lds[64 * 66];
  const int hb = blockIdx.x >> 5, tc = blockIdx.x & 31;
  const int t0 = tc * 64, tid = threadIdx.x;
#pragma unroll
  for (int i = 0; i < 2; i++) {
    int idx = i * 2048 + tid * 8;
    int tl = idx >> 6, d0 = idx & 63;
    int r = hb * 2048 + t0 + tl;
    const u16* src = &qkv[(size_t)(r >> 4) * 3072 + 2048 + (r & 15) * 64 + d0];
    uint4 v = *(const uint4*)src;
    u16* dst = &lds[tl * 66 + d0];
    *(unsigned*)(dst + 0) = v.x; *(unsigned*)(dst + 2) = v.y;
    *(unsigned*)(dst + 4) = v.z; *(unsigned*)(dst + 6) = v.w;
  }
  __syncthreads();
#pragma unroll
  for (int i = 0; i < 2; i++) {
    int idx = i * 2048 + tid * 8;
    int d = idx >> 6, tl0 = idx & 63;
    union { u16 u[8]; uint4 v; } ou;
#pragma unroll
    for (int e = 0; e < 8; e++) ou.u[e] = lds[(tl0 + e) * 66 + d];
    *(uint4*)&vt[(size_t)hb * 131072 + (size_t)d * 2048 + t0 + tl0] = ou.v;
  }
}

// ---------------- flash attention (causal), 32x32 MFMA, in-register P ------
// R12 best-known structure (74us): 4-wave blocks (128 q-rows), qb 0..15,
// grid 1024, double-buffered K/V (32 KB), VGPR 72, no-max exp2 softmax,
// cvt_pk+permlane32_swap in-register P. lp uses a pairwise tree (chain 16->5).

__global__ __launch_bounds__(256)
void attn_kernel(const u16* __restrict__ qkv, const u16* __restrict__ vtg,
                 u16* __restrict__ att) {
  __shared__ u16 k_lds[2][64 * 64];
  __shared__ u16 v_lds[2][64 * 64];

  const int xcd = blockIdx.x & 7;
  const int c = blockIdx.x >> 3;          // 0..127 within XCD
  const int hb = xcd * 8 + (c & 7);       // hb-contiguous per XCD
  const int qb = 15 - (c >> 3);           // heavy blocks first (LPT)
  const int tid = threadIdx.x;
  const int lane = tid & 63, w = tid >> 6;
  const int l31 = lane & 31, l5 = lane >> 5;
  const int qbase = qb * 128 + w * 32;
  const int nkt = 2 * qb + 2;

  bf16x8 qf[4];
  {
    int t = qbase + l31;
    int r = hb * 2048 + t;
    size_t base = (size_t)(r >> 4) * 3072 + (r & 15) * 64;
#pragma unroll
    for (int d = 0; d < 4; d++)
      qf[d] = *(const bf16x8*)&qkv[base + d * 16 + l5 * 8];
  }

  f32x16 o0 = {}, o1 = {};
  float lp = 0.f;

  auto STAGE = [&](int buf, int kt) {
#pragma unroll
    for (int i = 0; i < 2; i++) {
      int U = i * 2048 + tid * 8;
      int row = U >> 6;
      int chunk = ((U >> 3) & 7) ^ (row & 7);
      int rK = hb * 2048 + kt * 64 + row;
      gload_lds16(&qkv[(size_t)(rK >> 4) * 3072 + 1024 + (rK & 15) * 64 + chunk * 8],
                  &k_lds[buf][U]);
    }
#pragma unroll
    for (int i = 0; i < 2; i++) {
      int U = i * 2048 + tid * 8;
      int row = U >> 6;
      int chunk = ((U >> 3) & 7) ^ (row & 7);
      gload_lds16(&vtg[(size_t)hb * 131072 + (size_t)row * 2048 + kt * 64 + chunk * 8],
                  &v_lds[buf][U]);
    }
  };

  STAGE(0, 0);
  asm volatile("s_waitcnt vmcnt(0)" ::: "memory");
  BAR();

  for (int kt = 0; kt < nkt; kt++) {
    if (kt + 1 < nkt) STAGE((kt + 1) & 1, kt + 1);
    const int cur = kt & 1;
    const bool active = (kt * 64 <= qbase + 31);
    if (active) {
      const bool full = (kt * 64 + 63 <= qbase);
      const int q = qbase + l31;
#pragma unroll
      for (int kb = 0; kb < 2; kb++) {
        int krow = kb * 32 + l31;
        int ksw = krow & 7;
        f32x16 st = {};
        __builtin_amdgcn_s_setprio(1);
#pragma unroll
        for (int t = 0; t < 4; t++) {
          bf16x8 kf = *(const bf16x8*)&k_lds[cur][krow * 64 + ((t * 2 + l5) ^ ksw) * 8];
          st = MFMA32(kf, qf[t], st);
        }
        __builtin_amdgcn_s_setprio(0);
        float p[16];
#pragma unroll
        for (int r = 0; r < 16; r++) {
          float v = st[r];
          if (!full) {
            int k = kt * 64 + kb * 32 + (r & 3) + 8 * (r >> 2) + 4 * l5;
            v = (k > q) ? -INFINITY : v;
          }
          p[r] = exp2_hw(v);
        }
        // pairwise tree-sum: same op count, dependent chain 16 -> ~5
        float ps = (((p[0] + p[1]) + (p[2] + p[3])) + ((p[4] + p[5]) + (p[6] + p[7]))) +
                   (((p[8] + p[9]) + (p[10] + p[11])) + ((p[12] + p[13]) + (p[14] + p[15])));
        lp += ps;
#pragma unroll
        for (int kc = 0; kc < 2; kc++) {
          unsigned w0 = cvt_pk_bf16(p[kc * 8 + 0], p[kc * 8 + 1]);
          unsigned w1 = cvt_pk_bf16(p[kc * 8 + 2], p[kc * 8 + 3]);
          unsigned w2 = cvt_pk_bf16(p[kc * 8 + 4], p[kc * 8 + 5]);
          unsigned w3 = cvt_pk_bf16(p[kc * 8 + 6], p[kc * 8 + 7]);
          uint2v sw0 = __builtin_amdgcn_permlane32_swap(w0, w2, false, false);
          uint2v sw1 = __builtin_amdgcn_permlane32_swap(w1, w3, false, false);
          union { unsigned u[4]; bf16x8 v; } pf;
          pf.u[0] = sw0.x; pf.u[1] = sw1.x; pf.u[2] = sw0.y; pf.u[3] = sw1.y;
          __builtin_amdgcn_s_setprio(1);
          {
            int row0 = l31;
            int ch0 = (kb * 4 + kc * 2 + l5) ^ (row0 & 7);
            bf16x8 vf0 = *(const bf16x8*)&v_lds[cur][row0 * 64 + ch0 * 8];
            o0 = MFMA32(vf0, pf.v, o0);
            int row1 = 32 + l31;
            int ch1 = (kb * 4 + kc * 2 + l5) ^ (row1 & 7);
            bf16x8 vf1 = *(const bf16x8*)&v_lds[cur][row1 * 64 + ch1 * 8];
            o1 = MFMA32(vf1, pf.v, o1);
          }
          __builtin_amdgcn_s_setprio(0);
        }
      }
    }
    asm volatile("s_waitcnt vmcnt(0)" ::: "memory");
    BAR();
  }

  lp += __shfl_xor(lp, 32);
  float rl = 1.f / lp;
  {
    int q = qbase + l31;
    size_t rbase = ((size_t)hb * 2048 + q) * 64;
#pragma unroll
    for (int g = 0; g < 4; g++) {
      uint2 wv;
      wv.x = cvt_pk_bf16(o0[4 * g + 0] * rl, o0[4 * g + 1] * rl);
      wv.y = cvt_pk_bf16(o0[4 * g + 2] * rl, o0[4 * g + 3] * rl);
      *(uint2*)&att[rbase + g * 8 + 4 * l5] = wv;
      uint2 wu;
      wu.x = cvt_pk_bf16(o1[4 * g + 0] * rl, o1[4 * g + 1] * rl);
      wu.y = cvt_pk_bf16(o1[4 * g + 2] * rl, o1[4 * g + 3] * rl);
      *(uint2*)&att[rbase + 32 + g * 8 + 4 * l5] = wu;
    }
  }
}

// ---------------- launch ----------------

extern "C" void kernel_launch(void* const* d_in, const int* in_sizes, int n_in,
                              void* d_out, int out_size, void* d_ws, size_t ws_size,
                              hipStream_t stream) {
  const float* x  = (const float*)d_in[0];
  const float* Wq = (const float*)d_in[1];
  const float* Wk = (const float*)d_in[2];
  const float* Wv = (const float*)d_in[3];
  const float* pw = (const float*)d_in[4];
  const float* pb = (const float*)d_in[5];
  float* out = (float*)d_out;

  char* ws = (char*)d_ws;
  u16* Xb   = (u16*)(ws);                       // 16 MB (dead after GEMM1)
  u16* VTg  = (u16*)(ws);                       // 16 MB (overlays Xb)
  u16* Wcat = (u16*)(ws + (16u << 20));         // 6 MB
  u16* PWt  = (u16*)(ws + (22u << 20));         // 2 MB
  u16* QKV  = (u16*)(ws + (24u << 20));         // 48 MB
  u16* ATT  = (u16*)(ws + (72u << 20));         // 16 MB (total 88 MB)

  prep_kernel<<<9984, 256, 0, stream>>>(x, Wq, Wk, Wv, pw, Xb, Wcat, PWt);

  gemm3b<1><<<768, 512, 0, stream>>>(Xb, Wcat, QKV, nullptr, 8192, 3072, 1024, 1024);

  vt_build<<<2048, 256, 0, stream>>>(QKV, VTg);

  attn_kernel<<<1024, 256, 0, stream>>>(QKV, VTg, ATT);

  gemm3b<0><<<256, 512, 0, stream>>>(ATT, PWt, out, pb, 8192, 1024, 1024, 0);
}